// Round 8
// baseline (149.629 us; speedup 1.0000x reference)
//
#include <hip/hip_runtime.h>

typedef float  f32x4  __attribute__((ext_vector_type(4)));
typedef short  bf16x8 __attribute__((ext_vector_type(8)));

#define NN 2048
#define CC 64

#define WAITVM(N) asm volatile("s_waitcnt vmcnt(" #N ")" ::: "memory")
#define LGKM0     asm volatile("s_waitcnt lgkmcnt(0)" ::: "memory")
#define SCHED0    __builtin_amdgcn_sched_barrier(0)

__device__ __forceinline__ unsigned short f2bf(float f) {
  union { float f; unsigned u; } v; v.f = f;
  unsigned r = v.u + 0x7fffu + ((v.u >> 16) & 1u);
  return (unsigned short)(r >> 16);
}

__device__ __forceinline__ void gll16(const void* g, void* l) {
  __builtin_amdgcn_global_load_lds(
      (const __attribute__((address_space(1))) unsigned int*)g,
      (__attribute__((address_space(3))) unsigned int*)l, 16, 0, 0);
}

// ---------------- per-layer linear: Mt = (H*Wm^T)^T bf16, S = H*Ws^T + b ----------------
__global__ __launch_bounds__(256) void gcn_linear(
    const float* __restrict__ H, const float* __restrict__ Wm,
    const float* __restrict__ Ws, const float* __restrict__ bias,
    unsigned short* __restrict__ Mt, float* __restrict__ S)
{
  const int bid = blockIdx.x;
  const int b   = bid >> 5;
  const int n0  = (bid & 31) << 6;
  const int tid = threadIdx.x;

  __shared__ float4 Hl[1024];
  __shared__ float4 Wm4[1024];
  __shared__ float4 Ws4[1024];

  const float4* Hg  = reinterpret_cast<const float4*>(H + ((size_t)b * NN + n0) * CC);
  const float4* Wmg = reinterpret_cast<const float4*>(Wm);
  const float4* Wsg = reinterpret_cast<const float4*>(Ws);
#pragma unroll
  for (int i = 0; i < 4; ++i) {
    int f = tid + 256 * i;
    Hl[f] = Hg[f];
    int o = f >> 4, c4 = f & 15;
    int slot = (o << 4) | (c4 ^ (o & 15));
    Wm4[slot] = Wmg[f];
    Ws4[slot] = Wsg[f];
  }
  __syncthreads();

  const int o = tid & 63, wv = tid >> 6;
  float accm[16], accs[16];
#pragma unroll
  for (int p = 0; p < 16; ++p) { accm[p] = 0.f; accs[p] = 0.f; }

  for (int c4 = 0; c4 < 16; ++c4) {
    int slot = (o << 4) | (c4 ^ (o & 15));
    float4 wm  = Wm4[slot];
    float4 wsv = Ws4[slot];
#pragma unroll
    for (int p = 0; p < 16; ++p) {
      float4 h = Hl[((wv << 4) + p) * 16 + c4];
      accm[p] += h.x * wm.x  + h.y * wm.y  + h.z * wm.z  + h.w * wm.w;
      accs[p] += h.x * wsv.x + h.y * wsv.y + h.z * wsv.z + h.w * wsv.w;
    }
  }

  const float bv = bias[o];
  bf16x8 m0, m1;
#pragma unroll
  for (int p = 0; p < 8; ++p) { m0[p] = (short)f2bf(accm[p]); m1[p] = (short)f2bf(accm[8 + p]); }
  unsigned short* mp = Mt + ((size_t)b * CC + o) * NN + n0 + (wv << 4);
  *reinterpret_cast<bf16x8*>(mp)     = m0;
  *reinterpret_cast<bf16x8*>(mp + 8) = m1;
#pragma unroll
  for (int p = 0; p < 16; ++p) {
    int r = n0 + (wv << 4) + p;
    S[((size_t)b * NN + r) * CC + o] = accs[p] + bv;
  }
}

// ---------------- layer-0 GEMM (fp32 A): gll+LDS staging, fragment-layout Abf store ----
// block = 16 rows x 8 waves; wave w: j-chunk [w*256,+256), 4 K-tiles of 64.
// DT=0: fp32 A in, Abf (fragment layout) out. DT=2: fp32 A, no store (fallback).
template<int DT>
__global__ __launch_bounds__(512) void gcn_gemm_f32(
    const float* __restrict__ A, unsigned short* __restrict__ Abf,
    const unsigned short* __restrict__ Mt, const float* __restrict__ S,
    float* __restrict__ H, const int relu)
{
  __shared__ char smem[65536];

  const int bid = blockIdx.x;
  const int b   = bid >> 7;
  const int rb  = bid & 127;
  const int n0  = rb << 4;
  const int tid  = threadIdx.x;
  const int w    = tid >> 6;
  const int lane = tid & 63;
  const int fr   = lane & 15, g = lane >> 4;
  const int j0   = w << 8;

  char* ring = smem + w * 8192;    // 2 slots x 4096 B (fp32 16x64 tile)

  const float* Ag = A + ((size_t)(b * NN + n0)) * NN + j0;
  const size_t wgid = (size_t)bid * 8 + w;
  const unsigned short* Mb = Mt + ((size_t)b * CC + fr) * NN + j0 + (g << 3);
  unsigned short* abw = Abf + wgid * 4096 + (size_t)lane * 16;  // fragment layout

  auto issueA = [&](int t, int s) {
    const int rl = lane >> 4, cl = lane & 15;
#pragma unroll
    for (int q = 0; q < 4; ++q) {
      int row = (q << 2) + rl;
      int c16 = cl ^ (row & 7);               // pre-swizzled source (T21)
      gll16(Ag + (size_t)row * NN + t * 64 + c16 * 4,
            ring + s * 4096 + (q << 10));     // linear LDS dest
    }
  };

  auto loadB = [&](bf16x8* Bv, int t) {
#pragma unroll
    for (int kk = 0; kk < 2; ++kk)
#pragma unroll
      for (int n = 0; n < 4; ++n)
        Bv[kk * 4 + n] = *reinterpret_cast<const bf16x8*>(
            Mb + (size_t)(n << 4) * NN + t * 64 + (kk << 5));
  };

  auto readA = [&](int s, int t, bf16x8* af) {
    const float4* sh = reinterpret_cast<const float4*>(ring + s * 4096);
    float4 v[4];
#pragma unroll
    for (int kk = 0; kk < 2; ++kk) {
      v[2 * kk]     = sh[(fr << 4) + (((kk << 3) + (g << 1))     ^ (fr & 7))];
      v[2 * kk + 1] = sh[(fr << 4) + (((kk << 3) + (g << 1) + 1) ^ (fr & 7))];
    }
    LGKM0; SCHED0;
#pragma unroll
    for (int kk = 0; kk < 2; ++kk) {
      af[kk][0] = (short)f2bf(v[2 * kk].x);     af[kk][1] = (short)f2bf(v[2 * kk].y);
      af[kk][2] = (short)f2bf(v[2 * kk].z);     af[kk][3] = (short)f2bf(v[2 * kk].w);
      af[kk][4] = (short)f2bf(v[2 * kk + 1].x); af[kk][5] = (short)f2bf(v[2 * kk + 1].y);
      af[kk][6] = (short)f2bf(v[2 * kk + 1].z); af[kk][7] = (short)f2bf(v[2 * kk + 1].w);
    }
    if constexpr (DT == 0) {
      *reinterpret_cast<bf16x8*>(abw + (size_t)t * 1024)     = af[0];
      *reinterpret_cast<bf16x8*>(abw + (size_t)t * 1024 + 8) = af[1];
    }
  };

  f32x4 acc[4];
#pragma unroll
  for (int n = 0; n < 4; ++n) acc[n] = (f32x4){0.f, 0.f, 0.f, 0.f};

  auto mfma8 = [&](bf16x8* af, bf16x8* Bv) {
#pragma unroll
    for (int kk = 0; kk < 2; ++kk)
#pragma unroll
      for (int n = 0; n < 4; ++n)
        acc[n] = __builtin_amdgcn_mfma_f32_16x16x32_bf16(af[kk], Bv[kk * 4 + n], acc[n], 0, 0, 0);
  };

  bf16x8 B0[8], B1[8], B2[8], B3[8], af[2];

  loadB(B0, 0);
  issueA(0, 0); issueA(1, 1);

  WAITVM(4);
  readA(0, 0, af); loadB(B1, 1); issueA(2, 0); mfma8(af, B0);

  if constexpr (DT == 0) { WAITVM(14); } else { WAITVM(12); }
  readA(1, 1, af); loadB(B2, 2); issueA(3, 1); mfma8(af, B1);

  if constexpr (DT == 0) { WAITVM(14); } else { WAITVM(12); }
  readA(0, 2, af); loadB(B3, 3); mfma8(af, B2);

  if constexpr (DT == 0) { WAITVM(10); } else { WAITVM(8); }
  readA(1, 3, af); mfma8(af, B3);

  // ---- cross-wave reduction ----
  __syncthreads();
  float* red = reinterpret_cast<float*>(smem);   // [8 waves][16 rows][64 cols]
#pragma unroll
  for (int n = 0; n < 4; ++n)
#pragma unroll
    for (int r = 0; r < 4; ++r)
      red[(w << 10) + (((g << 2) + r) << 6) + (n << 4) + fr] = acc[n][r];
  __syncthreads();
  {
    const int row = tid >> 5;
    const int col = (tid & 31) << 1;
    float2 v = make_float2(0.f, 0.f);
#pragma unroll
    for (int ww = 0; ww < 8; ++ww) {
      float2 p = *reinterpret_cast<const float2*>(&red[(ww << 10) + (row << 6) + col]);
      v.x += p.x; v.y += p.y;
    }
    const size_t idx = ((size_t)b * NN + n0 + row) * CC + col;
    float2 s = *reinterpret_cast<const float2*>(&S[idx]);
    v.x += s.x; v.y += s.y;
    if (relu) { v.x = fmaxf(v.x, 0.f); v.y = fmaxf(v.y, 0.f); }
    *reinterpret_cast<float2*>(&H[idx]) = v;
  }
}

// ---------------- layers 1,2 GEMM (bf16 fragment-layout Abf): LDS-free A path ----------
// Same geometry as layer 0; A-fragments loaded directly to VGPRs (2x16B per tile),
// depth-2 prefetch pinned by sched_barrier(0). LDS used only for the reduction.
__global__ __launch_bounds__(512, 4) void gcn_gemm_bf16(
    const unsigned short* __restrict__ Abf, const unsigned short* __restrict__ Mt,
    const float* __restrict__ S, float* __restrict__ H, const int relu)
{
  __shared__ char smem[32768];

  const int bid = blockIdx.x;
  const int b   = bid >> 7;
  const int rb  = bid & 127;
  const int n0  = rb << 4;
  const int tid  = threadIdx.x;
  const int w    = tid >> 6;
  const int lane = tid & 63;
  const int fr   = lane & 15, g = lane >> 4;
  const int j0   = w << 8;

  const size_t wgid = (size_t)bid * 8 + w;
  const unsigned short* abr = Abf + wgid * 4096 + (size_t)lane * 16;
  const unsigned short* Mb  = Mt + ((size_t)b * CC + fr) * NN + j0 + (g << 3);

  auto lda = [&](bf16x8* af, int t) {
    af[0] = *reinterpret_cast<const bf16x8*>(abr + (size_t)t * 1024);
    af[1] = *reinterpret_cast<const bf16x8*>(abr + (size_t)t * 1024 + 8);
  };
  auto loadB = [&](bf16x8* Bv, int t) {
#pragma unroll
    for (int kk = 0; kk < 2; ++kk)
#pragma unroll
      for (int n = 0; n < 4; ++n)
        Bv[kk * 4 + n] = *reinterpret_cast<const bf16x8*>(
            Mb + (size_t)(n << 4) * NN + t * 64 + (kk << 5));
  };

  f32x4 acc[4];
#pragma unroll
  for (int n = 0; n < 4; ++n) acc[n] = (f32x4){0.f, 0.f, 0.f, 0.f};

  auto mfma8 = [&](bf16x8* af, bf16x8* Bv) {
#pragma unroll
    for (int kk = 0; kk < 2; ++kk)
#pragma unroll
      for (int n = 0; n < 4; ++n)
        acc[n] = __builtin_amdgcn_mfma_f32_16x16x32_bf16(af[kk], Bv[kk * 4 + n], acc[n], 0, 0, 0);
  };

  bf16x8 a0[2], a1[2], B[8];
  lda(a0, 0);
  // t0
  loadB(B, 0); lda(a1, 1); SCHED0; mfma8(a0, B);
  // t1
  loadB(B, 1); lda(a0, 2); SCHED0; mfma8(a1, B);
  // t2
  loadB(B, 2); lda(a1, 3); SCHED0; mfma8(a0, B);
  // t3
  loadB(B, 3); SCHED0; mfma8(a1, B);

  // ---- cross-wave reduction ----
  __syncthreads();
  float* red = reinterpret_cast<float*>(smem);   // [8 waves][16 rows][64 cols]
#pragma unroll
  for (int n = 0; n < 4; ++n)
#pragma unroll
    for (int r = 0; r < 4; ++r)
      red[(w << 10) + (((g << 2) + r) << 6) + (n << 4) + fr] = acc[n][r];
  __syncthreads();
  {
    const int row = tid >> 5;
    const int col = (tid & 31) << 1;
    float2 v = make_float2(0.f, 0.f);
#pragma unroll
    for (int ww = 0; ww < 8; ++ww) {
      float2 p = *reinterpret_cast<const float2*>(&red[(ww << 10) + (row << 6) + col]);
      v.x += p.x; v.y += p.y;
    }
    const size_t idx = ((size_t)b * NN + n0 + row) * CC + col;
    float2 s = *reinterpret_cast<const float2*>(&S[idx]);
    v.x += s.x; v.y += s.y;
    if (relu) { v.x = fmaxf(v.x, 0.f); v.y = fmaxf(v.y, 0.f); }
    *reinterpret_cast<float2*>(&H[idx]) = v;
  }
}

extern "C" void kernel_launch(void* const* d_in, const int* in_sizes, int n_in,
                              void* d_out, int out_size, void* d_ws, size_t ws_size,
                              hipStream_t stream)
{
  const float* X = (const float*)d_in[0];
  const float* A = (const float*)d_in[1];
  const size_t MB = 1024 * 1024;
  unsigned short* Mt  = (unsigned short*)d_ws;                      // 2 MiB
  float*          S   = (float*)((char*)d_ws + 2 * MB);             // 4 MiB
  unsigned short* Abf = (unsigned short*)((char*)d_ws + 6 * MB);    // 64 MiB fragment bf16 A
  const bool has_abf = ws_size >= 70 * MB;
  float* H = (float*)d_out;

  for (int l = 0; l < 3; ++l) {
    const float* Wm = (const float*)d_in[2 + 3 * l];
    const float* Ws = (const float*)d_in[3 + 3 * l];
    const float* bb = (const float*)d_in[4 + 3 * l];
    const int relu = (l < 2) ? 1 : 0;
    gcn_linear<<<dim3(256), dim3(256), 0, stream>>>((l == 0) ? X : H, Wm, Ws, bb, Mt, S);
    if (has_abf) {
      if (l == 0)
        gcn_gemm_f32<0><<<dim3(1024), dim3(512), 0, stream>>>(A, Abf, Mt, S, H, relu);
      else
        gcn_gemm_bf16<<<dim3(1024), dim3(512), 0, stream>>>(Abf, Mt, S, H, relu);
    } else {
      gcn_gemm_f32<2><<<dim3(1024), dim3(512), 0, stream>>>(A, (unsigned short*)d_ws, Mt, S, H, relu);
    }
  }
}

// Round 9
// 137.358 us; speedup vs baseline: 1.0893x; 1.0893x over previous
//
#include <hip/hip_runtime.h>

typedef float  f32x4  __attribute__((ext_vector_type(4)));
typedef short  bf16x8 __attribute__((ext_vector_type(8)));

#define NN 2048
#define CC 64

#define WAITVM(N) asm volatile("s_waitcnt vmcnt(" #N ")" ::: "memory")
#define LGKM0     asm volatile("s_waitcnt lgkmcnt(0)" ::: "memory")
#define SCHED0    __builtin_amdgcn_sched_barrier(0)

__device__ __forceinline__ unsigned short f2bf(float f) {
  union { float f; unsigned u; } v; v.f = f;
  unsigned r = v.u + 0x7fffu + ((v.u >> 16) & 1u);
  return (unsigned short)(r >> 16);
}

__device__ __forceinline__ void gll16(const void* g, void* l) {
  __builtin_amdgcn_global_load_lds(
      (const __attribute__((address_space(1))) unsigned int*)g,
      (__attribute__((address_space(3))) unsigned int*)l, 16, 0, 0);
}

// ---------------- per-layer linear: Mt = (H*Wm^T)^T bf16, S = H*Ws^T + b ----------------
__global__ __launch_bounds__(256) void gcn_linear(
    const float* __restrict__ H, const float* __restrict__ Wm,
    const float* __restrict__ Ws, const float* __restrict__ bias,
    unsigned short* __restrict__ Mt, float* __restrict__ S)
{
  const int bid = blockIdx.x;
  const int b   = bid >> 5;
  const int n0  = (bid & 31) << 6;
  const int tid = threadIdx.x;

  __shared__ float4 Hl[1024];
  __shared__ float4 Wm4[1024];
  __shared__ float4 Ws4[1024];

  const float4* Hg  = reinterpret_cast<const float4*>(H + ((size_t)b * NN + n0) * CC);
  const float4* Wmg = reinterpret_cast<const float4*>(Wm);
  const float4* Wsg = reinterpret_cast<const float4*>(Ws);
#pragma unroll
  for (int i = 0; i < 4; ++i) {
    int f = tid + 256 * i;
    Hl[f] = Hg[f];
    int o = f >> 4, c4 = f & 15;
    int slot = (o << 4) | (c4 ^ (o & 15));
    Wm4[slot] = Wmg[f];
    Ws4[slot] = Wsg[f];
  }
  __syncthreads();

  const int o = tid & 63, wv = tid >> 6;
  float accm[16], accs[16];
#pragma unroll
  for (int p = 0; p < 16; ++p) { accm[p] = 0.f; accs[p] = 0.f; }

  for (int c4 = 0; c4 < 16; ++c4) {
    int slot = (o << 4) | (c4 ^ (o & 15));
    float4 wm  = Wm4[slot];
    float4 wsv = Ws4[slot];
#pragma unroll
    for (int p = 0; p < 16; ++p) {
      float4 h = Hl[((wv << 4) + p) * 16 + c4];
      accm[p] += h.x * wm.x  + h.y * wm.y  + h.z * wm.z  + h.w * wm.w;
      accs[p] += h.x * wsv.x + h.y * wsv.y + h.z * wsv.z + h.w * wsv.w;
    }
  }

  const float bv = bias[o];
  bf16x8 m0, m1;
#pragma unroll
  for (int p = 0; p < 8; ++p) { m0[p] = (short)f2bf(accm[p]); m1[p] = (short)f2bf(accm[8 + p]); }
  unsigned short* mp = Mt + ((size_t)b * CC + o) * NN + n0 + (wv << 4);
  *reinterpret_cast<bf16x8*>(mp)     = m0;
  *reinterpret_cast<bf16x8*>(mp + 8) = m1;
#pragma unroll
  for (int p = 0; p < 16; ++p) {
    int r = n0 + (wv << 4) + p;
    S[((size_t)b * NN + r) * CC + o] = accs[p] + bv;
  }
}

// ---------------- layer-0 GEMM (fp32 A): gll+LDS staging, row-major Abf store ----------
// block = 16 rows x 8 waves; wave w: j-chunk [w*256,+256), 4 K-tiles of 64.
// DT=0: fp32 A in, row-major bf16 Abf out. DT=2: fp32 A, no store (fallback).
template<int DT>
__global__ __launch_bounds__(512) void gcn_gemm_f32(
    const float* __restrict__ A, unsigned short* __restrict__ Abf,
    const unsigned short* __restrict__ Mt, const float* __restrict__ S,
    float* __restrict__ H, const int relu)
{
  __shared__ char smem[65536];

  const int bid = blockIdx.x;
  const int b   = bid >> 7;
  const int rb  = bid & 127;
  const int n0  = rb << 4;
  const int tid  = threadIdx.x;
  const int w    = tid >> 6;
  const int lane = tid & 63;
  const int fr   = lane & 15, g = lane >> 4;
  const int j0   = w << 8;

  char* ring = smem + w * 8192;    // 2 slots x 4096 B (fp32 16x64 tile)

  const float* Ag = A + ((size_t)(b * NN + n0)) * NN + j0;
  const unsigned short* Mb = Mt + ((size_t)b * CC + fr) * NN + j0 + (g << 3);
  // row-major bf16 Abf destination for this wave's fragments
  unsigned short* abw = Abf + ((size_t)(b * NN + n0 + fr)) * NN + j0 + (g << 3);

  auto issueA = [&](int t, int s) {
    const int rl = lane >> 4, cl = lane & 15;
#pragma unroll
    for (int q = 0; q < 4; ++q) {
      int row = (q << 2) + rl;
      int c16 = cl ^ (row & 7);               // pre-swizzled source (T21)
      gll16(Ag + (size_t)row * NN + t * 64 + c16 * 4,
            ring + s * 4096 + (q << 10));     // linear LDS dest
    }
  };

  auto loadB = [&](bf16x8* Bv, int t) {
#pragma unroll
    for (int kk = 0; kk < 2; ++kk)
#pragma unroll
      for (int n = 0; n < 4; ++n)
        Bv[kk * 4 + n] = *reinterpret_cast<const bf16x8*>(
            Mb + (size_t)(n << 4) * NN + t * 64 + (kk << 5));
  };

  auto readA = [&](int s, int t, bf16x8* af) {
    const float4* sh = reinterpret_cast<const float4*>(ring + s * 4096);
    float4 v[4];
#pragma unroll
    for (int kk = 0; kk < 2; ++kk) {
      v[2 * kk]     = sh[(fr << 4) + (((kk << 3) + (g << 1))     ^ (fr & 7))];
      v[2 * kk + 1] = sh[(fr << 4) + (((kk << 3) + (g << 1) + 1) ^ (fr & 7))];
    }
    LGKM0; SCHED0;
#pragma unroll
    for (int kk = 0; kk < 2; ++kk) {
      af[kk][0] = (short)f2bf(v[2 * kk].x);     af[kk][1] = (short)f2bf(v[2 * kk].y);
      af[kk][2] = (short)f2bf(v[2 * kk].z);     af[kk][3] = (short)f2bf(v[2 * kk].w);
      af[kk][4] = (short)f2bf(v[2 * kk + 1].x); af[kk][5] = (short)f2bf(v[2 * kk + 1].y);
      af[kk][6] = (short)f2bf(v[2 * kk + 1].z); af[kk][7] = (short)f2bf(v[2 * kk + 1].w);
    }
    if constexpr (DT == 0) {
      // af[kk] = A[n0+fr][j0 + t*64 + kk*32 + g*8 .. +8]  (row-major store)
      *reinterpret_cast<bf16x8*>(abw + t * 64)      = af[0];
      *reinterpret_cast<bf16x8*>(abw + t * 64 + 32) = af[1];
    }
  };

  f32x4 acc[4];
#pragma unroll
  for (int n = 0; n < 4; ++n) acc[n] = (f32x4){0.f, 0.f, 0.f, 0.f};

  auto mfma8 = [&](bf16x8* af, bf16x8* Bv) {
#pragma unroll
    for (int kk = 0; kk < 2; ++kk)
#pragma unroll
      for (int n = 0; n < 4; ++n)
        acc[n] = __builtin_amdgcn_mfma_f32_16x16x32_bf16(af[kk], Bv[kk * 4 + n], acc[n], 0, 0, 0);
  };

  bf16x8 B0[8], B1[8], B2[8], B3[8], af[2];

  loadB(B0, 0);
  issueA(0, 0); issueA(1, 1);

  WAITVM(4);
  readA(0, 0, af); loadB(B1, 1); issueA(2, 0); mfma8(af, B0);

  if constexpr (DT == 0) { WAITVM(14); } else { WAITVM(12); }
  readA(1, 1, af); loadB(B2, 2); issueA(3, 1); mfma8(af, B1);

  if constexpr (DT == 0) { WAITVM(14); } else { WAITVM(12); }
  readA(0, 2, af); loadB(B3, 3); mfma8(af, B2);

  if constexpr (DT == 0) { WAITVM(10); } else { WAITVM(8); }
  readA(1, 3, af); mfma8(af, B3);

  // ---- cross-wave reduction ----
  __syncthreads();
  float* red = reinterpret_cast<float*>(smem);   // [8 waves][16 rows][64 cols]
#pragma unroll
  for (int n = 0; n < 4; ++n)
#pragma unroll
    for (int r = 0; r < 4; ++r)
      red[(w << 10) + (((g << 2) + r) << 6) + (n << 4) + fr] = acc[n][r];
  __syncthreads();
  {
    const int row = tid >> 5;
    const int col = (tid & 31) << 1;
    float2 v = make_float2(0.f, 0.f);
#pragma unroll
    for (int ww = 0; ww < 8; ++ww) {
      float2 p = *reinterpret_cast<const float2*>(&red[(ww << 10) + (row << 6) + col]);
      v.x += p.x; v.y += p.y;
    }
    const size_t idx = ((size_t)b * NN + n0 + row) * CC + col;
    float2 s = *reinterpret_cast<const float2*>(&S[idx]);
    v.x += s.x; v.y += s.y;
    if (relu) { v.x = fmaxf(v.x, 0.f); v.y = fmaxf(v.y, 0.f); }
    *reinterpret_cast<float2*>(&H[idx]) = v;
  }
}

// ---------------- layers 1,2 GEMM (row-major bf16 Abf), 2 row-tiles x 4 col-tiles/wave ----
// block = 512 thr = 8 waves, 32 rows; wave w: k-chunk [w*256,+256), 8 K-tiles of 32.
// Per K-tile: 2 A-frag + 4 B-frag loads -> 8 MFMA. Triple-buffer depth-2 prefetch,
// static (t%3) indices (compile-time after unroll), sched_barrier(0) pins issue order.
__global__ __launch_bounds__(512) void gcn_gemm_bf16(
    const unsigned short* __restrict__ Abf, const unsigned short* __restrict__ Mt,
    const float* __restrict__ S, float* __restrict__ H, const int relu)
{
  __shared__ float red[8192];   // 4 slots x [32 rows][64 cols] f32 = 32 KB

  const int bid  = blockIdx.x;   // 512 blocks: b = bid>>6, rowgroup = bid&63
  const int b    = bid >> 6;
  const int row0 = (bid & 63) << 5;
  const int tid  = threadIdx.x;
  const int w    = tid >> 6;
  const int lane = tid & 63;
  const int fr   = lane & 15, g = lane >> 4;
  const int k0   = w << 8;

  const unsigned short* Ab = Abf + ((size_t)b * NN + row0) * NN + k0 + (g << 3);
  const unsigned short* Mb = Mt  + ((size_t)b * CC) * NN + k0 + (g << 3);

  auto ldA = [&](bf16x8* a, int t) {
    a[0] = *reinterpret_cast<const bf16x8*>(Ab + (size_t)fr * NN        + t * 32);
    a[1] = *reinterpret_cast<const bf16x8*>(Ab + (size_t)(16 + fr) * NN + t * 32);
  };
  auto ldB = [&](bf16x8* bv, int t) {
#pragma unroll
    for (int n = 0; n < 4; ++n)
      bv[n] = *reinterpret_cast<const bf16x8*>(Mb + (size_t)((n << 4) + fr) * NN + t * 32);
  };

  f32x4 acc[2][4];
#pragma unroll
  for (int m = 0; m < 2; ++m)
#pragma unroll
    for (int n = 0; n < 4; ++n) acc[m][n] = (f32x4){0.f, 0.f, 0.f, 0.f};

  bf16x8 Ar[3][2], Br[3][4];
  ldA(Ar[0], 0); ldB(Br[0], 0);
  ldA(Ar[1], 1); ldB(Br[1], 1);

#pragma unroll
  for (int t = 0; t < 8; ++t) {
    if (t < 6) { ldA(Ar[(t + 2) % 3], t + 2); ldB(Br[(t + 2) % 3], t + 2); }
    SCHED0;
#pragma unroll
    for (int m = 0; m < 2; ++m)
#pragma unroll
      for (int n = 0; n < 4; ++n)
        acc[m][n] = __builtin_amdgcn_mfma_f32_16x16x32_bf16(
            Ar[t % 3][m], Br[t % 3][n], acc[m][n], 0, 0, 0);
    SCHED0;
  }

  // ---- staged log2(8) reduction; swizzled LDS (2-way conflicts only) ----
  // partial layout: row = m*16 + g*4 + r (0..31), col = n*16 + fr; slot stride 2048 f32
#define RIDX(SLOT, ROW, COL) (((SLOT) << 11) + ((ROW) << 6) + ((COL) ^ ((((ROW) >> 2) & 3) << 4)))
  auto dump = [&](int slot) {
#pragma unroll
    for (int m = 0; m < 2; ++m)
#pragma unroll
      for (int n = 0; n < 4; ++n)
#pragma unroll
        for (int r = 0; r < 4; ++r)
          red[RIDX(slot, (m << 4) + (g << 2) + r, (n << 4) + fr)] = acc[m][n][r];
  };
  auto addin = [&](int slot) {
#pragma unroll
    for (int m = 0; m < 2; ++m)
#pragma unroll
      for (int n = 0; n < 4; ++n)
#pragma unroll
        for (int r = 0; r < 4; ++r)
          acc[m][n][r] += red[RIDX(slot, (m << 4) + (g << 2) + r, (n << 4) + fr)];
  };

  if (w >= 4) dump(w - 4);
  __syncthreads();
  if (w < 4) addin(w);
  __syncthreads();
  if (w == 2 || w == 3) dump(w - 2);
  __syncthreads();
  if (w < 2) addin(w);
  __syncthreads();
  if (w == 1) dump(0);
  __syncthreads();
  if (w == 0) { addin(0); dump(0); }
  __syncthreads();

  // cooperative epilogue: 512 thr x float4 covers 32x64
  {
    const int idx = tid << 2;
    const int row = idx >> 6, col = idx & 63;
    const float* rp = &red[RIDX(0, row, col)];
    float4 v = *reinterpret_cast<const float4*>(rp);
    const size_t o = ((size_t)b * NN + row0 + row) * CC + col;
    float4 s = *reinterpret_cast<const float4*>(&S[o]);
    v.x += s.x; v.y += s.y; v.z += s.z; v.w += s.w;
    if (relu) {
      v.x = fmaxf(v.x, 0.f); v.y = fmaxf(v.y, 0.f);
      v.z = fmaxf(v.z, 0.f); v.w = fmaxf(v.w, 0.f);
    }
    *reinterpret_cast<float4*>(&H[o]) = v;
  }
#undef RIDX
}

extern "C" void kernel_launch(void* const* d_in, const int* in_sizes, int n_in,
                              void* d_out, int out_size, void* d_ws, size_t ws_size,
                              hipStream_t stream)
{
  const float* X = (const float*)d_in[0];
  const float* A = (const float*)d_in[1];
  const size_t MB = 1024 * 1024;
  unsigned short* Mt  = (unsigned short*)d_ws;                      // 2 MiB
  float*          S   = (float*)((char*)d_ws + 2 * MB);             // 4 MiB
  unsigned short* Abf = (unsigned short*)((char*)d_ws + 6 * MB);    // 64 MiB row-major bf16 A
  const bool has_abf = ws_size >= 70 * MB;
  float* H = (float*)d_out;

  for (int l = 0; l < 3; ++l) {
    const float* Wm = (const float*)d_in[2 + 3 * l];
    const float* Ws = (const float*)d_in[3 + 3 * l];
    const float* bb = (const float*)d_in[4 + 3 * l];
    const int relu = (l < 2) ? 1 : 0;
    gcn_linear<<<dim3(256), dim3(256), 0, stream>>>((l == 0) ? X : H, Wm, Ws, bb, Mt, S);
    if (has_abf) {
      if (l == 0)
        gcn_gemm_f32<0><<<dim3(1024), dim3(512), 0, stream>>>(A, Abf, Mt, S, H, relu);
      else
        gcn_gemm_bf16<<<dim3(512), dim3(512), 0, stream>>>(Abf, Mt, S, H, relu);
    } else {
      gcn_gemm_f32<2><<<dim3(1024), dim3(512), 0, stream>>>(A, (unsigned short*)d_ws, Mt, S, H, relu);
    }
  }
}

// Round 10
// 134.788 us; speedup vs baseline: 1.1101x; 1.0191x over previous
//
#include <hip/hip_runtime.h>

typedef float  f32x4  __attribute__((ext_vector_type(4)));
typedef short  bf16x8 __attribute__((ext_vector_type(8)));

#define NN 2048
#define CC 64

#define WAITVM(N) asm volatile("s_waitcnt vmcnt(" #N ")" ::: "memory")
#define LGKM0     asm volatile("s_waitcnt lgkmcnt(0)" ::: "memory")
#define SCHED0    __builtin_amdgcn_sched_barrier(0)
// pinned 16B global load: cannot be sunk/reordered among volatile asm
#define GLOAD(DST, PTR, IMM) \
  asm volatile("global_load_dwordx4 %0, %1, off offset:%2" : "=v"(DST) : "v"(PTR), "i"(IMM))
#define GSTORE(PTR, V) \
  asm volatile("global_store_dwordx4 %0, %1, off" :: "v"(PTR), "v"(V) : "memory")

__device__ __forceinline__ unsigned short f2bf(float f) {
  union { float f; unsigned u; } v; v.f = f;
  unsigned r = v.u + 0x7fffu + ((v.u >> 16) & 1u);
  return (unsigned short)(r >> 16);
}

__device__ __forceinline__ void gll16(const void* g, void* l) {
  __builtin_amdgcn_global_load_lds(
      (const __attribute__((address_space(1))) unsigned int*)g,
      (__attribute__((address_space(3))) unsigned int*)l, 16, 0, 0);
}

// ---------------- per-layer linear: Mt = (H*Wm^T)^T bf16, S = H*Ws^T + b ----------------
__global__ __launch_bounds__(256) void gcn_linear(
    const float* __restrict__ H, const float* __restrict__ Wm,
    const float* __restrict__ Ws, const float* __restrict__ bias,
    unsigned short* __restrict__ Mt, float* __restrict__ S)
{
  const int bid = blockIdx.x;
  const int b   = bid >> 5;
  const int n0  = (bid & 31) << 6;
  const int tid = threadIdx.x;

  __shared__ float4 Hl[1024];
  __shared__ float4 Wm4[1024];
  __shared__ float4 Ws4[1024];

  const float4* Hg  = reinterpret_cast<const float4*>(H + ((size_t)b * NN + n0) * CC);
  const float4* Wmg = reinterpret_cast<const float4*>(Wm);
  const float4* Wsg = reinterpret_cast<const float4*>(Ws);
#pragma unroll
  for (int i = 0; i < 4; ++i) {
    int f = tid + 256 * i;
    Hl[f] = Hg[f];
    int o = f >> 4, c4 = f & 15;
    int slot = (o << 4) | (c4 ^ (o & 15));
    Wm4[slot] = Wmg[f];
    Ws4[slot] = Wsg[f];
  }
  __syncthreads();

  const int o = tid & 63, wv = tid >> 6;
  float accm[16], accs[16];
#pragma unroll
  for (int p = 0; p < 16; ++p) { accm[p] = 0.f; accs[p] = 0.f; }

  for (int c4 = 0; c4 < 16; ++c4) {
    int slot = (o << 4) | (c4 ^ (o & 15));
    float4 wm  = Wm4[slot];
    float4 wsv = Ws4[slot];
#pragma unroll
    for (int p = 0; p < 16; ++p) {
      float4 h = Hl[((wv << 4) + p) * 16 + c4];
      accm[p] += h.x * wm.x  + h.y * wm.y  + h.z * wm.z  + h.w * wm.w;
      accs[p] += h.x * wsv.x + h.y * wsv.y + h.z * wsv.z + h.w * wsv.w;
    }
  }

  const float bv = bias[o];
  bf16x8 m0, m1;
#pragma unroll
  for (int p = 0; p < 8; ++p) { m0[p] = (short)f2bf(accm[p]); m1[p] = (short)f2bf(accm[8 + p]); }
  unsigned short* mp = Mt + ((size_t)b * CC + o) * NN + n0 + (wv << 4);
  *reinterpret_cast<bf16x8*>(mp)     = m0;
  *reinterpret_cast<bf16x8*>(mp + 8) = m1;
#pragma unroll
  for (int p = 0; p < 16; ++p) {
    int r = n0 + (wv << 4) + p;
    S[((size_t)b * NN + r) * CC + o] = accs[p] + bv;
  }
}

// ---------------- layer-0 GEMM (fp32 A): gll+LDS A staging, asm-pinned B ring ----------
// block = 16 rows x 8 waves; wave w: j-chunk [w*256,+256), 4 K-tiles of 64.
// All vm-ops are volatile asm / gll intrinsics -> program-order vmcnt counting is exact.
// Wait ladder (both DT): 4,4,4,0.  DT=0: also stores row-major bf16 Abf.
template<int DT>
__global__ __launch_bounds__(512) void gcn_gemm_f32(
    const float* __restrict__ A, unsigned short* __restrict__ Abf,
    const unsigned short* __restrict__ Mt, const float* __restrict__ S,
    float* __restrict__ H, const int relu)
{
  __shared__ char smem[65536];

  const int bid = blockIdx.x;
  const int b   = bid >> 7;
  const int rb  = bid & 127;
  const int n0  = rb << 4;
  const int tid  = threadIdx.x;
  const int w    = tid >> 6;
  const int lane = tid & 63;
  const int fr   = lane & 15, g = lane >> 4;
  const int j0   = w << 8;

  char* ring = smem + w * 8192;    // 2 slots x 4096 B (fp32 16x64 tile)

  const float* Ag = A + ((size_t)(b * NN + n0)) * NN + j0;
  const unsigned short* Mb = Mt + ((size_t)b * CC + fr) * NN + j0 + (g << 3);
  unsigned short* abw = Abf + ((size_t)(b * NN + n0 + fr)) * NN + j0 + (g << 3);

  const unsigned short* pB[8];
#pragma unroll
  for (int kk = 0; kk < 2; ++kk)
#pragma unroll
    for (int n = 0; n < 4; ++n)
      pB[kk * 4 + n] = Mb + (size_t)(n << 4) * NN + (kk << 5);

  auto issueA = [&](int t, int s) {
    const int rl = lane >> 4, cl = lane & 15;
#pragma unroll
    for (int q = 0; q < 4; ++q) {
      int row = (q << 2) + rl;
      int c16 = cl ^ (row & 7);               // pre-swizzled source (T21)
      gll16(Ag + (size_t)row * NN + t * 64 + c16 * 4,
            ring + s * 4096 + (q << 10));     // linear LDS dest
    }
  };

  auto readA = [&](int s, int t, bf16x8* af) {
    const float4* sh = reinterpret_cast<const float4*>(ring + s * 4096);
    float4 v[4];
#pragma unroll
    for (int kk = 0; kk < 2; ++kk) {
      v[2 * kk]     = sh[(fr << 4) + (((kk << 3) + (g << 1))     ^ (fr & 7))];
      v[2 * kk + 1] = sh[(fr << 4) + (((kk << 3) + (g << 1) + 1) ^ (fr & 7))];
    }
    LGKM0; SCHED0;
#pragma unroll
    for (int kk = 0; kk < 2; ++kk) {
      af[kk][0] = (short)f2bf(v[2 * kk].x);     af[kk][1] = (short)f2bf(v[2 * kk].y);
      af[kk][2] = (short)f2bf(v[2 * kk].z);     af[kk][3] = (short)f2bf(v[2 * kk].w);
      af[kk][4] = (short)f2bf(v[2 * kk + 1].x); af[kk][5] = (short)f2bf(v[2 * kk + 1].y);
      af[kk][6] = (short)f2bf(v[2 * kk + 1].z); af[kk][7] = (short)f2bf(v[2 * kk + 1].w);
    }
    if constexpr (DT == 0) {
      GSTORE(abw + t * 64,      af[0]);
      GSTORE(abw + t * 64 + 32, af[1]);
    }
  };

  f32x4 acc[4];
#pragma unroll
  for (int n = 0; n < 4; ++n) acc[n] = (f32x4){0.f, 0.f, 0.f, 0.f};

  auto mfma8 = [&](bf16x8* af, bf16x8* Bv) {
#pragma unroll
    for (int kk = 0; kk < 2; ++kk)
#pragma unroll
      for (int n = 0; n < 4; ++n)
        acc[n] = __builtin_amdgcn_mfma_f32_16x16x32_bf16(af[kk], Bv[kk * 4 + n], acc[n], 0, 0, 0);
  };

#define LOADB(SLOT, T) do {                              \
    _Pragma("unroll")                                    \
    for (int i_ = 0; i_ < 8; ++i_)                       \
      GLOAD(Br[SLOT][i_], pB[i_], (T) * 128);            \
  } while (0)

  bf16x8 Br[2][8], af[2];

  LOADB(0, 0);                 // [B0:8]
  issueA(0, 0); issueA(1, 1);  // [+A0:4 +A1:4 = 16]
  WAITVM(4); SCHED0;           // drain B0,A0; rem {A1}
  readA(0, 0, af);             // st0 (+2 if DT==0)
  LOADB(1, 1); issueA(2, 0);   // +B1:8 +A2:4
  mfma8(af, Br[0]);
  WAITVM(4); SCHED0;           // drain A1,(st0),B1; rem {A2}
  readA(1, 1, af);
  LOADB(0, 2); issueA(3, 1);
  mfma8(af, Br[1]);
  WAITVM(4); SCHED0;           // drain A2,(st1),B2; rem {A3}
  readA(0, 2, af);
  LOADB(1, 3);
  mfma8(af, Br[0]);
  WAITVM(0); SCHED0;           // drain A3,B3,(st2)
  readA(1, 3, af);
  mfma8(af, Br[1]);
#undef LOADB

  // ---- cross-wave reduction ----
  __syncthreads();
  float* red = reinterpret_cast<float*>(smem);   // [8 waves][16 rows][64 cols]
#pragma unroll
  for (int n = 0; n < 4; ++n)
#pragma unroll
    for (int r = 0; r < 4; ++r)
      red[(w << 10) + (((g << 2) + r) << 6) + (n << 4) + fr] = acc[n][r];
  __syncthreads();
  {
    const int row = tid >> 5;
    const int col = (tid & 31) << 1;
    float2 v = make_float2(0.f, 0.f);
#pragma unroll
    for (int ww = 0; ww < 8; ++ww) {
      float2 p = *reinterpret_cast<const float2*>(&red[(ww << 10) + (row << 6) + col]);
      v.x += p.x; v.y += p.y;
    }
    const size_t idx = ((size_t)b * NN + n0 + row) * CC + col;
    float2 s = *reinterpret_cast<const float2*>(&S[idx]);
    v.x += s.x; v.y += s.y;
    if (relu) { v.x = fmaxf(v.x, 0.f); v.y = fmaxf(v.y, 0.f); }
    *reinterpret_cast<float2*>(&H[idx]) = v;
  }
}

// ---------------- layers 1,2 GEMM (row-major bf16 Abf): asm-pinned depth-3 ring ----------
// block = 8 waves, 32 rows; wave w: k-chunk [w*256,+256), 8 K-tiles of 32.
// Per tile: 2 A + 4 B asm loads -> 8 MFMA. Ring depth 3: tiles t+1,t+2 always in flight
// (12 outstanding loads); WAITVM(12)->6->0 ladder; SCHED0 stops MFMA hoisting (rule #18).
__global__ __launch_bounds__(512) void gcn_gemm_bf16(
    const unsigned short* __restrict__ Abf, const unsigned short* __restrict__ Mt,
    const float* __restrict__ S, float* __restrict__ H, const int relu)
{
  __shared__ float red[8192];   // 4 slots x [32 rows][64 cols] f32 = 32 KB

  const int bid  = blockIdx.x;   // 512 blocks: b = bid>>6, rowgroup = bid&63
  const int b    = bid >> 6;
  const int row0 = (bid & 63) << 5;
  const int tid  = threadIdx.x;
  const int w    = tid >> 6;
  const int lane = tid & 63;
  const int fr   = lane & 15, g = lane >> 4;
  const int k0   = w << 8;

  const unsigned short* Ab = Abf + ((size_t)b * NN + row0) * NN + k0 + (g << 3);
  const unsigned short* Mb = Mt  + ((size_t)b * CC) * NN + k0 + (g << 3);

  const unsigned short* pA0 = Ab + (size_t)fr * NN;
  const unsigned short* pA1 = Ab + (size_t)(16 + fr) * NN;
  const unsigned short* pB[4];
#pragma unroll
  for (int n = 0; n < 4; ++n)
    pB[n] = Mb + (size_t)((n << 4) + fr) * NN;

  f32x4 acc[2][4];
#pragma unroll
  for (int m = 0; m < 2; ++m)
#pragma unroll
    for (int n = 0; n < 4; ++n) acc[m][n] = (f32x4){0.f, 0.f, 0.f, 0.f};

  bf16x8 Ar[3][2], Br[3][4];

#define BLOADT(SLOT, T) do {                             \
    GLOAD(Ar[SLOT][0], pA0, (T) * 64);                   \
    GLOAD(Ar[SLOT][1], pA1, (T) * 64);                   \
    _Pragma("unroll")                                    \
    for (int n_ = 0; n_ < 4; ++n_)                       \
      GLOAD(Br[SLOT][n_], pB[n_], (T) * 64);             \
  } while (0)

#define BSTEP(T, W) do {                                                        \
    WAITVM(W); SCHED0;                                                          \
    _Pragma("unroll")                                                           \
    for (int m_ = 0; m_ < 2; ++m_)                                              \
      _Pragma("unroll")                                                         \
      for (int n_ = 0; n_ < 4; ++n_)                                            \
        acc[m_][n_] = __builtin_amdgcn_mfma_f32_16x16x32_bf16(                  \
            Ar[(T) % 3][m_], Br[(T) % 3][n_], acc[m_][n_], 0, 0, 0);            \
    if ((T) + 3 < 8) BLOADT(((T) + 3) % 3, (T) + 3);                            \
  } while (0)

  BLOADT(0, 0); BLOADT(1, 1); BLOADT(2, 2);   // 18 loads in flight
  BSTEP(0, 12); BSTEP(1, 12); BSTEP(2, 12); BSTEP(3, 12);
  BSTEP(4, 12); BSTEP(5, 12); BSTEP(6, 6);  BSTEP(7, 0);
#undef BSTEP
#undef BLOADT

  // ---- staged log2(8) reduction; swizzled LDS (2-way conflicts only) ----
#define RIDX(SLOT, ROW, COL) (((SLOT) << 11) + ((ROW) << 6) + ((COL) ^ ((((ROW) >> 2) & 3) << 4)))
  auto dump = [&](int slot) {
#pragma unroll
    for (int m = 0; m < 2; ++m)
#pragma unroll
      for (int n = 0; n < 4; ++n)
#pragma unroll
        for (int r = 0; r < 4; ++r)
          red[RIDX(slot, (m << 4) + (g << 2) + r, (n << 4) + fr)] = acc[m][n][r];
  };
  auto addin = [&](int slot) {
#pragma unroll
    for (int m = 0; m < 2; ++m)
#pragma unroll
      for (int n = 0; n < 4; ++n)
#pragma unroll
        for (int r = 0; r < 4; ++r)
          acc[m][n][r] += red[RIDX(slot, (m << 4) + (g << 2) + r, (n << 4) + fr)];
  };

  if (w >= 4) dump(w - 4);
  __syncthreads();
  if (w < 4) addin(w);
  __syncthreads();
  if (w == 2 || w == 3) dump(w - 2);
  __syncthreads();
  if (w < 2) addin(w);
  __syncthreads();
  if (w == 1) dump(0);
  __syncthreads();
  if (w == 0) { addin(0); dump(0); }
  __syncthreads();

  {
    const int idx = tid << 2;
    const int row = idx >> 6, col = idx & 63;
    const float* rp = &red[RIDX(0, row, col)];
    float4 v = *reinterpret_cast<const float4*>(rp);
    const size_t o = ((size_t)b * NN + row0 + row) * CC + col;
    float4 s = *reinterpret_cast<const float4*>(&S[o]);
    v.x += s.x; v.y += s.y; v.z += s.z; v.w += s.w;
    if (relu) {
      v.x = fmaxf(v.x, 0.f); v.y = fmaxf(v.y, 0.f);
      v.z = fmaxf(v.z, 0.f); v.w = fmaxf(v.w, 0.f);
    }
    *reinterpret_cast<float4*>(&H[o]) = v;
  }
#undef RIDX
}

extern "C" void kernel_launch(void* const* d_in, const int* in_sizes, int n_in,
                              void* d_out, int out_size, void* d_ws, size_t ws_size,
                              hipStream_t stream)
{
  const float* X = (const float*)d_in[0];
  const float* A = (const float*)d_in[1];
  const size_t MB = 1024 * 1024;
  unsigned short* Mt  = (unsigned short*)d_ws;                      // 2 MiB
  float*          S   = (float*)((char*)d_ws + 2 * MB);             // 4 MiB
  unsigned short* Abf = (unsigned short*)((char*)d_ws + 6 * MB);    // 64 MiB row-major bf16 A
  const bool has_abf = ws_size >= 70 * MB;
  float* H = (float*)d_out;

  for (int l = 0; l < 3; ++l) {
    const float* Wm = (const float*)d_in[2 + 3 * l];
    const float* Ws = (const float*)d_in[3 + 3 * l];
    const float* bb = (const float*)d_in[4 + 3 * l];
    const int relu = (l < 2) ? 1 : 0;
    gcn_linear<<<dim3(256), dim3(256), 0, stream>>>((l == 0) ? X : H, Wm, Ws, bb, Mt, S);
    if (has_abf) {
      if (l == 0)
        gcn_gemm_f32<0><<<dim3(1024), dim3(512), 0, stream>>>(A, Abf, Mt, S, H, relu);
      else
        gcn_gemm_bf16<<<dim3(512), dim3(512), 0, stream>>>(Abf, Mt, S, H, relu);
    } else {
      gcn_gemm_f32<2><<<dim3(1024), dim3(512), 0, stream>>>(A, (unsigned short*)d_ws, Mt, S, H, relu);
    }
  }
}

// Round 11
// 116.769 us; speedup vs baseline: 1.2814x; 1.1543x over previous
//
#include <hip/hip_runtime.h>

typedef float  f32x4  __attribute__((ext_vector_type(4)));
typedef short  bf16x8 __attribute__((ext_vector_type(8)));

#define NN 2048
#define CC 64

#define WAITVM(N) asm volatile("s_waitcnt vmcnt(" #N ")" ::: "memory")
#define LGKM0     asm volatile("s_waitcnt lgkmcnt(0)" ::: "memory")
#define SCHED0    __builtin_amdgcn_sched_barrier(0)
#define GLOAD(DST, PTR, IMM) \
  asm volatile("global_load_dwordx4 %0, %1, off offset:%2" : "=v"(DST) : "v"(PTR), "i"(IMM))
#define GSTORE(PTR, V) \
  asm volatile("global_store_dwordx4 %0, %1, off" :: "v"(PTR), "v"(V) : "memory")

__device__ __forceinline__ unsigned short f2bf(float f) {
  union { float f; unsigned u; } v; v.f = f;
  unsigned r = v.u + 0x7fffu + ((v.u >> 16) & 1u);
  return (unsigned short)(r >> 16);
}

__device__ __forceinline__ bf16x8 pack8(float4 a, float4 b) {
  bf16x8 p;
  p[0] = (short)f2bf(a.x); p[1] = (short)f2bf(a.y);
  p[2] = (short)f2bf(a.z); p[3] = (short)f2bf(a.w);
  p[4] = (short)f2bf(b.x); p[5] = (short)f2bf(b.y);
  p[6] = (short)f2bf(b.z); p[7] = (short)f2bf(b.w);
  return p;
}

__device__ __forceinline__ void gll16(const void* g, void* l) {
  __builtin_amdgcn_global_load_lds(
      (const __attribute__((address_space(1))) unsigned int*)g,
      (__attribute__((address_space(3))) unsigned int*)l, 16, 0, 0);
}

// ---------------- layer-0 linear (X input): Mt = (X*Wm^T)^T bf16, S = X*Ws^T + b ----------
__global__ __launch_bounds__(256) void gcn_linear(
    const float* __restrict__ H, const float* __restrict__ Wm,
    const float* __restrict__ Ws, const float* __restrict__ bias,
    unsigned short* __restrict__ Mt, float* __restrict__ S)
{
  const int bid = blockIdx.x;
  const int b   = bid >> 5;
  const int n0  = (bid & 31) << 6;
  const int tid = threadIdx.x;

  __shared__ float4 Hl[1024];
  __shared__ float4 Wm4[1024];
  __shared__ float4 Ws4[1024];

  const float4* Hg  = reinterpret_cast<const float4*>(H + ((size_t)b * NN + n0) * CC);
  const float4* Wmg = reinterpret_cast<const float4*>(Wm);
  const float4* Wsg = reinterpret_cast<const float4*>(Ws);
#pragma unroll
  for (int i = 0; i < 4; ++i) {
    int f = tid + 256 * i;
    Hl[f] = Hg[f];
    int o = f >> 4, c4 = f & 15;
    int slot = (o << 4) | (c4 ^ (o & 15));
    Wm4[slot] = Wmg[f];
    Ws4[slot] = Wsg[f];
  }
  __syncthreads();

  const int o = tid & 63, wv = tid >> 6;
  float accm[16], accs[16];
#pragma unroll
  for (int p = 0; p < 16; ++p) { accm[p] = 0.f; accs[p] = 0.f; }

  for (int c4 = 0; c4 < 16; ++c4) {
    int slot = (o << 4) | (c4 ^ (o & 15));
    float4 wm  = Wm4[slot];
    float4 wsv = Ws4[slot];
#pragma unroll
    for (int p = 0; p < 16; ++p) {
      float4 h = Hl[((wv << 4) + p) * 16 + c4];
      accm[p] += h.x * wm.x  + h.y * wm.y  + h.z * wm.z  + h.w * wm.w;
      accs[p] += h.x * wsv.x + h.y * wsv.y + h.z * wsv.z + h.w * wsv.w;
    }
  }

  const float bv = bias[o];
  bf16x8 m0, m1;
#pragma unroll
  for (int p = 0; p < 8; ++p) { m0[p] = (short)f2bf(accm[p]); m1[p] = (short)f2bf(accm[8 + p]); }
  unsigned short* mp = Mt + ((size_t)b * CC + o) * NN + n0 + (wv << 4);
  *reinterpret_cast<bf16x8*>(mp)     = m0;
  *reinterpret_cast<bf16x8*>(mp + 8) = m1;
#pragma unroll
  for (int p = 0; p < 16; ++p) {
    int r = n0 + (wv << 4) + p;
    S[((size_t)b * NN + r) * CC + o] = accs[p] + bv;
  }
}

// ---- fused next-layer linear tail: Hb (bf16, swizzled) @ {Wm,Ws}^T -> MtN, SN ----
// Precondition: Hb at smem[0..], Wm-bf16 at smem+16384, Ws-bf16 at smem+24576 (all
// XOR-swizzled byte ^= (row&7)<<4), barrier passed. RT = row-tiles (rows = RT*16).
// waves 0-3: Mt output (col-tile = w); waves 4-7: S output (col-tile = w-4).
template<int RT>
__device__ __forceinline__ void lin_mfma_store(
    const char* smem, const float* __restrict__ bias,
    unsigned short* __restrict__ MtN, float* __restrict__ SN,
    int b, int row0, int tid)
{
  const int lane = tid & 63, w = tid >> 6, fr = lane & 15, g = lane >> 4;
  const char* Hb = smem;
  const char* Wb = smem + 16384 + ((w >> 2) << 13);
  const int ct = w & 3;
  const int o  = (ct << 4) | fr;

  bf16x8 bf[2];
#pragma unroll
  for (int kk = 0; kk < 2; ++kk) {
    unsigned boff = (unsigned)(o * 128 + kk * 64 + g * 16) ^ (unsigned)((o & 7) << 4);
    bf[kk] = *reinterpret_cast<const bf16x8*>(Wb + boff);
  }
  f32x4 acc[RT];
#pragma unroll
  for (int m = 0; m < RT; ++m) acc[m] = (f32x4){0.f, 0.f, 0.f, 0.f};
#pragma unroll
  for (int m = 0; m < RT; ++m)
#pragma unroll
    for (int kk = 0; kk < 2; ++kk) {
      const int hr = m * 16 + fr;
      unsigned hoff = (unsigned)(hr * 128 + kk * 64 + g * 16) ^ (unsigned)((hr & 7) << 4);
      bf16x8 hf = *reinterpret_cast<const bf16x8*>(Hb + hoff);
      acc[m] = __builtin_amdgcn_mfma_f32_16x16x32_bf16(hf, bf[kk], acc[m], 0, 0, 0);
    }

  if (w < 4) {      // M^T store: Mt[b][o][n], 4 consecutive n per lane -> 8B store
#pragma unroll
    for (int m = 0; m < RT; ++m) {
      ushort4 pk;
      pk.x = f2bf(acc[m][0]); pk.y = f2bf(acc[m][1]);
      pk.z = f2bf(acc[m][2]); pk.w = f2bf(acc[m][3]);
      *reinterpret_cast<ushort4*>(MtN + ((size_t)b * CC + o) * NN + row0 + m * 16 + (g << 2)) = pk;
    }
  } else {          // S store: S[b][n][o] = acc + bias[o]
    const float bv = bias[o];
#pragma unroll
    for (int m = 0; m < RT; ++m)
#pragma unroll
      for (int r = 0; r < 4; ++r)
        SN[((size_t)b * NN + row0 + m * 16 + (g << 2) + r) * CC + o] = acc[m][r] + bv;
  }
}

// ---------------- layer-0 GEMM (fp32 A): gll+LDS A staging, asm-pinned B ring ----------
// DT=0: stores row-major bf16 Abf + fused linear-1 tail (no H write).
// DT=2: fallback, writes H with relu flag.
template<int DT>
__global__ __launch_bounds__(512) void gcn_gemm_f32(
    const float* __restrict__ A, unsigned short* __restrict__ Abf,
    const unsigned short* __restrict__ Mt, const float* __restrict__ S,
    float* __restrict__ H, const int relu,
    const float* __restrict__ WmN, const float* __restrict__ WsN,
    const float* __restrict__ biasN,
    unsigned short* __restrict__ MtN, float* __restrict__ SN)
{
  __shared__ char smem[65536];

  const int bid = blockIdx.x;
  const int b   = bid >> 7;
  const int rb  = bid & 127;
  const int n0  = rb << 4;
  const int tid  = threadIdx.x;
  const int w    = tid >> 6;
  const int lane = tid & 63;
  const int fr   = lane & 15, g = lane >> 4;
  const int j0   = w << 8;

  char* ring = smem + w * 8192;

  const float* Ag = A + ((size_t)(b * NN + n0)) * NN + j0;
  const unsigned short* Mb = Mt + ((size_t)b * CC + fr) * NN + j0 + (g << 3);
  unsigned short* abw = Abf + ((size_t)(b * NN + n0 + fr)) * NN + j0 + (g << 3);

  const unsigned short* pB[8];
#pragma unroll
  for (int kk = 0; kk < 2; ++kk)
#pragma unroll
    for (int n = 0; n < 4; ++n)
      pB[kk * 4 + n] = Mb + (size_t)(n << 4) * NN + (kk << 5);

  auto issueA = [&](int t, int s) {
    const int rl = lane >> 4, cl = lane & 15;
#pragma unroll
    for (int q = 0; q < 4; ++q) {
      int row = (q << 2) + rl;
      int c16 = cl ^ (row & 7);
      gll16(Ag + (size_t)row * NN + t * 64 + c16 * 4,
            ring + s * 4096 + (q << 10));
    }
  };

  auto readA = [&](int s, int t, bf16x8* af) {
    const float4* sh = reinterpret_cast<const float4*>(ring + s * 4096);
    float4 v[4];
#pragma unroll
    for (int kk = 0; kk < 2; ++kk) {
      v[2 * kk]     = sh[(fr << 4) + (((kk << 3) + (g << 1))     ^ (fr & 7))];
      v[2 * kk + 1] = sh[(fr << 4) + (((kk << 3) + (g << 1) + 1) ^ (fr & 7))];
    }
    LGKM0; SCHED0;
#pragma unroll
    for (int kk = 0; kk < 2; ++kk) {
      af[kk][0] = (short)f2bf(v[2 * kk].x);     af[kk][1] = (short)f2bf(v[2 * kk].y);
      af[kk][2] = (short)f2bf(v[2 * kk].z);     af[kk][3] = (short)f2bf(v[2 * kk].w);
      af[kk][4] = (short)f2bf(v[2 * kk + 1].x); af[kk][5] = (short)f2bf(v[2 * kk + 1].y);
      af[kk][6] = (short)f2bf(v[2 * kk + 1].z); af[kk][7] = (short)f2bf(v[2 * kk + 1].w);
    }
    if constexpr (DT == 0) {
      GSTORE(abw + t * 64,      af[0]);
      GSTORE(abw + t * 64 + 32, af[1]);
    }
  };

  f32x4 acc[4];
#pragma unroll
  for (int n = 0; n < 4; ++n) acc[n] = (f32x4){0.f, 0.f, 0.f, 0.f};

  auto mfma8 = [&](bf16x8* af, bf16x8* Bv) {
#pragma unroll
    for (int kk = 0; kk < 2; ++kk)
#pragma unroll
      for (int n = 0; n < 4; ++n)
        acc[n] = __builtin_amdgcn_mfma_f32_16x16x32_bf16(af[kk], Bv[kk * 4 + n], acc[n], 0, 0, 0);
  };

#define LOADB(SLOT, T) do {                              \
    _Pragma("unroll")                                    \
    for (int i_ = 0; i_ < 8; ++i_)                       \
      GLOAD(Br[SLOT][i_], pB[i_], (T) * 128);            \
  } while (0)

  bf16x8 Br[2][8], af[2];

  LOADB(0, 0);
  issueA(0, 0); issueA(1, 1);
  WAITVM(4); SCHED0;
  readA(0, 0, af);
  LOADB(1, 1); issueA(2, 0);
  mfma8(af, Br[0]);
  WAITVM(4); SCHED0;
  readA(1, 1, af);
  LOADB(0, 2); issueA(3, 1);
  mfma8(af, Br[1]);
  WAITVM(4); SCHED0;
  readA(0, 2, af);
  LOADB(1, 3);
  mfma8(af, Br[0]);
  WAITVM(0); SCHED0;
  readA(1, 3, af);
  mfma8(af, Br[1]);
#undef LOADB

  // ---- cross-wave reduction ----
  __syncthreads();
  float* red = reinterpret_cast<float*>(smem);   // [8 waves][16 rows][64 cols]
#pragma unroll
  for (int n = 0; n < 4; ++n)
#pragma unroll
    for (int r = 0; r < 4; ++r)
      red[(w << 10) + (((g << 2) + r) << 6) + (n << 4) + fr] = acc[n][r];
  __syncthreads();

  const int row = tid >> 5;
  const int col = (tid & 31) << 1;
  float2 v = make_float2(0.f, 0.f);
#pragma unroll
  for (int ww = 0; ww < 8; ++ww) {
    float2 p = *reinterpret_cast<const float2*>(&red[(ww << 10) + (row << 6) + col]);
    v.x += p.x; v.y += p.y;
  }
  const size_t idx = ((size_t)b * NN + n0 + row) * CC + col;
  float2 s = *reinterpret_cast<const float2*>(&S[idx]);
  v.x += s.x; v.y += s.y;

  if constexpr (DT == 2) {
    if (relu) { v.x = fmaxf(v.x, 0.f); v.y = fmaxf(v.y, 0.f); }
    *reinterpret_cast<float2*>(&H[idx]) = v;
  } else {
    // fused linear-1: relu, H-tile -> Hb bf16; weights -> LDS; MFMA tail.
    v.x = fmaxf(v.x, 0.f); v.y = fmaxf(v.y, 0.f);
    unsigned pk = (unsigned)f2bf(v.x) | ((unsigned)f2bf(v.y) << 16);
    const unsigned hb = (unsigned)(row * 128 + col * 2) ^ (unsigned)((row & 7) << 4);
    const int wi = tid * 8;
    float4 wa0 = *reinterpret_cast<const float4*>(WmN + wi);
    float4 wa1 = *reinterpret_cast<const float4*>(WmN + wi + 4);
    float4 ws0 = *reinterpret_cast<const float4*>(WsN + wi);
    float4 ws1 = *reinterpret_cast<const float4*>(WsN + wi + 4);
    __syncthreads();                       // red reads complete
    *reinterpret_cast<unsigned*>(smem + hb) = pk;     // Hb [16][64] bf16
    const int wo = tid >> 3;
    const unsigned wb = (unsigned)(wo * 128 + (tid & 7) * 16) ^ (unsigned)((wo & 7) << 4);
    *reinterpret_cast<bf16x8*>(smem + 16384 + wb) = pack8(wa0, wa1);
    *reinterpret_cast<bf16x8*>(smem + 24576 + wb) = pack8(ws0, ws1);
    __syncthreads();
    lin_mfma_store<1>(smem, biasN, MtN, SN, b, n0, tid);
  }
}

// ---------------- layers 1,2 GEMM (row-major bf16 Abf): asm-pinned depth-3 ring ----------
// FUSE=1: fused next-layer linear tail (no H write). FUSE=0: final layer, writes H.
template<int FUSE>
__global__ __launch_bounds__(512) void gcn_gemm_bf16(
    const unsigned short* __restrict__ Abf, const unsigned short* __restrict__ Mt,
    const float* __restrict__ S, float* __restrict__ H, const int relu,
    const float* __restrict__ WmN, const float* __restrict__ WsN,
    const float* __restrict__ biasN,
    unsigned short* __restrict__ MtN, float* __restrict__ SN)
{
  __shared__ char smem[32768];
  float* red = reinterpret_cast<float*>(smem);   // 4 slots x [32][64] f32

  const int bid  = blockIdx.x;
  const int b    = bid >> 6;
  const int row0 = (bid & 63) << 5;
  const int tid  = threadIdx.x;
  const int w    = tid >> 6;
  const int lane = tid & 63;
  const int fr   = lane & 15, g = lane >> 4;
  const int k0   = w << 8;

  const unsigned short* Ab = Abf + ((size_t)b * NN + row0) * NN + k0 + (g << 3);
  const unsigned short* Mb = Mt  + ((size_t)b * CC) * NN + k0 + (g << 3);

  const unsigned short* pA0 = Ab + (size_t)fr * NN;
  const unsigned short* pA1 = Ab + (size_t)(16 + fr) * NN;
  const unsigned short* pB[4];
#pragma unroll
  for (int n = 0; n < 4; ++n)
    pB[n] = Mb + (size_t)((n << 4) + fr) * NN;

  f32x4 acc[2][4];
#pragma unroll
  for (int m = 0; m < 2; ++m)
#pragma unroll
    for (int n = 0; n < 4; ++n) acc[m][n] = (f32x4){0.f, 0.f, 0.f, 0.f};

  bf16x8 Ar[3][2], Br[3][4];

#define BLOADT(SLOT, T) do {                             \
    GLOAD(Ar[SLOT][0], pA0, (T) * 64);                   \
    GLOAD(Ar[SLOT][1], pA1, (T) * 64);                   \
    _Pragma("unroll")                                    \
    for (int n_ = 0; n_ < 4; ++n_)                       \
      GLOAD(Br[SLOT][n_], pB[n_], (T) * 64);             \
  } while (0)

#define BSTEP(T, W) do {                                                        \
    WAITVM(W); SCHED0;                                                          \
    _Pragma("unroll")                                                           \
    for (int m_ = 0; m_ < 2; ++m_)                                              \
      _Pragma("unroll")                                                         \
      for (int n_ = 0; n_ < 4; ++n_)                                            \
        acc[m_][n_] = __builtin_amdgcn_mfma_f32_16x16x32_bf16(                  \
            Ar[(T) % 3][m_], Br[(T) % 3][n_], acc[m_][n_], 0, 0, 0);            \
    if ((T) + 3 < 8) BLOADT(((T) + 3) % 3, (T) + 3);                            \
  } while (0)

  BLOADT(0, 0); BLOADT(1, 1); BLOADT(2, 2);
  BSTEP(0, 12); BSTEP(1, 12); BSTEP(2, 12); BSTEP(3, 12);
  BSTEP(4, 12); BSTEP(5, 12); BSTEP(6, 6);  BSTEP(7, 0);
#undef BSTEP
#undef BLOADT

  // ---- staged log2(8) reduction ----
#define RIDX(SLOT, ROW, COL) (((SLOT) << 11) + ((ROW) << 6) + ((COL) ^ ((((ROW) >> 2) & 3) << 4)))
  auto dump = [&](int slot) {
#pragma unroll
    for (int m = 0; m < 2; ++m)
#pragma unroll
      for (int n = 0; n < 4; ++n)
#pragma unroll
        for (int r = 0; r < 4; ++r)
          red[RIDX(slot, (m << 4) + (g << 2) + r, (n << 4) + fr)] = acc[m][n][r];
  };
  auto addin = [&](int slot) {
#pragma unroll
    for (int m = 0; m < 2; ++m)
#pragma unroll
      for (int n = 0; n < 4; ++n)
#pragma unroll
        for (int r = 0; r < 4; ++r)
          acc[m][n][r] += red[RIDX(slot, (m << 4) + (g << 2) + r, (n << 4) + fr)];
  };

  if (w >= 4) dump(w - 4);
  __syncthreads();
  if (w < 4) addin(w);
  __syncthreads();
  if (w == 2 || w == 3) dump(w - 2);
  __syncthreads();
  if (w < 2) addin(w);
  __syncthreads();
  if (w == 1) dump(0);
  __syncthreads();
  if (w == 0) { addin(0); dump(0); }
  __syncthreads();

  const int idx = tid << 2;
  const int row = idx >> 6, col = idx & 63;
  float4 v = *reinterpret_cast<const float4*>(&red[RIDX(0, row, col)]);
  const size_t o = ((size_t)b * NN + row0 + row) * CC + col;
  float4 s = *reinterpret_cast<const float4*>(&S[o]);
  v.x += s.x; v.y += s.y; v.z += s.z; v.w += s.w;

  if constexpr (FUSE == 0) {
    if (relu) {
      v.x = fmaxf(v.x, 0.f); v.y = fmaxf(v.y, 0.f);
      v.z = fmaxf(v.z, 0.f); v.w = fmaxf(v.w, 0.f);
    }
    *reinterpret_cast<float4*>(&H[o]) = v;
  } else {
    v.x = fmaxf(v.x, 0.f); v.y = fmaxf(v.y, 0.f);
    v.z = fmaxf(v.z, 0.f); v.w = fmaxf(v.w, 0.f);
    ushort4 pk;
    pk.x = f2bf(v.x); pk.y = f2bf(v.y); pk.z = f2bf(v.z); pk.w = f2bf(v.w);
    const unsigned hb = (unsigned)(row * 128 + col * 2) ^ (unsigned)((row & 7) << 4);
    const int wi = tid * 8;
    float4 wa0 = *reinterpret_cast<const float4*>(WmN + wi);
    float4 wa1 = *reinterpret_cast<const float4*>(WmN + wi + 4);
    float4 ws0 = *reinterpret_cast<const float4*>(WsN + wi);
    float4 ws1 = *reinterpret_cast<const float4*>(WsN + wi + 4);
    __syncthreads();                       // red reads complete
    *reinterpret_cast<ushort4*>(smem + hb) = pk;      // Hb [32][64] bf16
    const int wo = tid >> 3;
    const unsigned wb = (unsigned)(wo * 128 + (tid & 7) * 16) ^ (unsigned)((wo & 7) << 4);
    *reinterpret_cast<bf16x8*>(smem + 16384 + wb) = pack8(wa0, wa1);
    *reinterpret_cast<bf16x8*>(smem + 24576 + wb) = pack8(ws0, ws1);
    __syncthreads();
    lin_mfma_store<2>(smem, biasN, MtN, SN, b, row0, tid);
  }
#undef RIDX
}

extern "C" void kernel_launch(void* const* d_in, const int* in_sizes, int n_in,
                              void* d_out, int out_size, void* d_ws, size_t ws_size,
                              hipStream_t stream)
{
  const float* X = (const float*)d_in[0];
  const float* A = (const float*)d_in[1];
  const float* Wm0 = (const float*)d_in[2],  *Ws0 = (const float*)d_in[3],  *b0 = (const float*)d_in[4];
  const float* Wm1 = (const float*)d_in[5],  *Ws1 = (const float*)d_in[6],  *b1 = (const float*)d_in[7];
  const float* Wm2 = (const float*)d_in[8],  *Ws2 = (const float*)d_in[9],  *b2 = (const float*)d_in[10];
  const size_t MB = 1024 * 1024;
  unsigned short* MtA = (unsigned short*)d_ws;                        // 2 MiB
  unsigned short* MtB = (unsigned short*)((char*)d_ws + 2 * MB);      // 2 MiB
  float*          SA  = (float*)((char*)d_ws + 4 * MB);               // 4 MiB
  float*          SB  = (float*)((char*)d_ws + 8 * MB);               // 4 MiB
  unsigned short* Abf = (unsigned short*)((char*)d_ws + 12 * MB);     // 64 MiB
  float* H = (float*)d_out;

  if (ws_size >= 76 * MB) {
    // 4-kernel fused pipeline
    gcn_linear<<<dim3(256), dim3(256), 0, stream>>>(X, Wm0, Ws0, b0, MtA, SA);
    gcn_gemm_f32<0><<<dim3(1024), dim3(512), 0, stream>>>(
        A, Abf, MtA, SA, nullptr, 1, Wm1, Ws1, b1, MtB, SB);
    gcn_gemm_bf16<1><<<dim3(512), dim3(512), 0, stream>>>(
        Abf, MtB, SB, nullptr, 1, Wm2, Ws2, b2, MtA, SA);
    gcn_gemm_bf16<0><<<dim3(512), dim3(512), 0, stream>>>(
        Abf, MtA, SA, H, 0, nullptr, nullptr, nullptr, nullptr, nullptr);
  } else {
    // fallback: per-layer linear + fp32 gemm, H ping-pong through d_out
    for (int l = 0; l < 3; ++l) {
      const float* Wm = (const float*)d_in[2 + 3 * l];
      const float* Ws = (const float*)d_in[3 + 3 * l];
      const float* bb = (const float*)d_in[4 + 3 * l];
      gcn_linear<<<dim3(256), dim3(256), 0, stream>>>((l == 0) ? X : H, Wm, Ws, bb, MtA, SA);
      gcn_gemm_f32<2><<<dim3(1024), dim3(512), 0, stream>>>(
          A, (unsigned short*)d_ws, MtA, SA, H, (l < 2) ? 1 : 0,
          nullptr, nullptr, nullptr, nullptr, nullptr);
    }
  }
}